// Round 3
// baseline (121.559 us; speedup 1.0000x reference)
//
#include <hip/hip_runtime.h>
#include <hip/hip_bf16.h>

#define BATCH 16384
#define DIM   512
#define UNITS 1024
// GAMMA = 0.5 is folded into the epilogue algebra: out = exp(c - 0.5*(xsq+musq))

typedef float v16f __attribute__((ext_vector_type(16)));

__device__ __forceinline__ void async_copy16(const void* g, void* l) {
    __builtin_amdgcn_global_load_lds(
        (const __attribute__((address_space(1))) void*)g,
        (__attribute__((address_space(3))) void*)l,
        16 /*bytes*/, 0 /*offset*/, 0 /*aux*/);
}

// mu [DIM][UNITS] fp32 -> Bt [UNITS][DIM] fp8(e4m3) via LDS transpose,
// plus per-column ||mu||^2 (fp32, computed pre-quantization).
__global__ __launch_bounds__(256)
void prep_b_kernel(const float* __restrict__ mu, unsigned char* __restrict__ Bt,
                   float* __restrict__ musq) {
    __shared__ float lds[64][65];
    __shared__ float red[64][4];
    const int t  = threadIdx.x;        // 256
    const int n0 = blockIdx.x * 64;
    const int c  = t & 63, r4 = t >> 6;     // load phase
    const int nl = t >> 2, kp = t & 3;      // write phase
    float s = 0.f;
    for (int kc = 0; kc < DIM; kc += 64) {
        __syncthreads();
#pragma unroll
        for (int i = 0; i < 16; i++)
            lds[r4 + i * 4][c] = mu[(size_t)(kc + r4 + i * 4) * UNITS + n0 + c];
        __syncthreads();
        int wr[4];
#pragma unroll
        for (int q = 0; q < 4; q++) {
            float f0 = lds[kp * 16 + q * 4 + 0][nl];
            float f1 = lds[kp * 16 + q * 4 + 1][nl];
            float f2 = lds[kp * 16 + q * 4 + 2][nl];
            float f3 = lds[kp * 16 + q * 4 + 3][nl];
            s += f0 * f0 + f1 * f1 + f2 * f2 + f3 * f3;
            int v = __builtin_amdgcn_cvt_pk_fp8_f32(f0, f1, 0, false);
            wr[q]  = __builtin_amdgcn_cvt_pk_fp8_f32(f2, f3, v, true);
        }
        *(int4*)(Bt + (size_t)(n0 + nl) * DIM + kc + kp * 16) =
            make_int4(wr[0], wr[1], wr[2], wr[3]);
    }
    red[nl][kp] = s;
    __syncthreads();
    if (t < 64) musq[n0 + t] = red[t][0] + red[t][1] + red[t][2] + red[t][3];
}

// B-resident fused RBF GEMM. 256 blocks (1/CU), 512 threads (8 waves).
// Block tile: 256 M x 256 N, K=512 in two LDS-resident halves of 256.
// Wave w owns rows [w*32, w*32+32) x all 256 cols: A fp32 from global ->
// fp8 in regs (xsq accumulated for free); B fp8 from swizzled LDS.
// ZERO barriers inside the MFMA loop (4 barriers total per block).
__global__ __launch_bounds__(512, 2)
void rbf_gemm_kernel(const float* __restrict__ A,
                     const unsigned char* __restrict__ Bt,
                     const float* __restrict__ musq,
                     float* __restrict__ out) {
    __shared__ __attribute__((aligned(16))) unsigned char Bs[256 * 256]; // 64 KB

    const int t  = threadIdx.x;
    const int l  = t & 63;
    const int w  = t >> 6;          // wave 0..7
    const int h  = l >> 5;          // k-half-of-frag select
    const int ln = l & 31;
    const int m0 = blockIdx.x * 256;
    const int n0 = blockIdx.y * 256;
    const int sx = l & 15;          // LDS slot-swizzle key ((j*32+ln)&15 == l&15)

    const int arow = m0 + w * 32 + ln;
    const float* Ap = A + (size_t)arow * DIM;

    v16f acc[8];
#pragma unroll
    for (int j = 0; j < 8; j++) acc[j] = (v16f)0.f;
    float xq = 0.f;

    for (int half = 0; half < 2; half++) {
        const int kc = half * 256;
        __syncthreads();   // half 1: all waves done reading Bs before overwrite
#pragma unroll
        for (int i = 0; i < 8; i++) {
            const int C  = i * 512 + t;              // 16B chunk index (lane-linear)
            const int n  = C >> 4;                   // row within tile
            const int sl = (C & 15) ^ (n & 15);      // logical 16B slot fetched
            async_copy16(Bt + (size_t)(n0 + n) * DIM + kc + sl * 16,
                         Bs + C * 16);
        }
        __syncthreads();

        const float* ap = Ap + kc + h * 8;
        const unsigned char* bbase = Bs + ln * 256 + h * 8;
#pragma unroll
        for (int s = 0; s < 16; s++) {
            float4 f0 = *(const float4*)(ap);
            float4 f1 = *(const float4*)(ap + 4);
            ap += 16;
            xq += f0.x * f0.x + f0.y * f0.y + f0.z * f0.z + f0.w * f0.w
                + f1.x * f1.x + f1.y * f1.y + f1.z * f1.z + f1.w * f1.w;
            int alo = __builtin_amdgcn_cvt_pk_fp8_f32(f0.x, f0.y, 0, false);
            alo     = __builtin_amdgcn_cvt_pk_fp8_f32(f0.z, f0.w, alo, true);
            int ahi = __builtin_amdgcn_cvt_pk_fp8_f32(f1.x, f1.y, 0, false);
            ahi     = __builtin_amdgcn_cvt_pk_fp8_f32(f1.z, f1.w, ahi, true);
            long a8 = ((long)(unsigned)ahi << 32) | (unsigned)alo;
            const unsigned char* bp = bbase + (s ^ sx) * 16;
#pragma unroll
            for (int j = 0; j < 8; j++) {
                long b8 = *(const long*)(bp + j * 8192);   // rows j*32, imm offset
                acc[j] = __builtin_amdgcn_mfma_f32_32x32x16_fp8_fp8(
                    a8, b8, acc[j], 0, 0, 0);
            }
        }
    }

    // xsq: lane holds half-K sum for its row; combine halves (row == ln for l and l^32)
    float xs = xq + __shfl_xor(xq, 32, 64);

    float mb[8];
#pragma unroll
    for (int j = 0; j < 8; j++) mb[j] = -0.5f * musq[n0 + j * 32 + ln];

    // C/D layout (verified m74/m101, dtype-indep): col = l&31,
    // row = (reg&3) + 8*(reg>>2) + 4*(l>>5)
#pragma unroll
    for (int rq = 0; rq < 4; rq++) {
#pragma unroll
        for (int rr = 0; rr < 4; rr++) {
            const int r    = rq * 4 + rr;
            const int rowp = rr + 8 * rq + 4 * h;
            const float xb = -0.5f * __shfl(xs, rowp, 64);
            float* orow = out + (size_t)(m0 + w * 32 + rowp) * UNITS + n0 + ln;
#pragma unroll
            for (int j = 0; j < 8; j++)
                orow[j * 32] = __expf(acc[j][r] + xb + mb[j]);
        }
    }
}

extern "C" void kernel_launch(void* const* d_in, const int* in_sizes, int n_in,
                              void* d_out, int out_size, void* d_ws, size_t ws_size,
                              hipStream_t stream) {
    const float* inputs = (const float*)d_in[0];   // [16384, 512] fp32
    const float* mu     = (const float*)d_in[1];   // [512, 1024] fp32
    float* out = (float*)d_out;                    // [16384, 1024] fp32

    char* ws = (char*)d_ws;
    unsigned char* Bt = (unsigned char*)ws;                      // 512 KiB fp8
    float* musq       = (float*)(ws + (size_t)UNITS * DIM);      // 4 KiB

    prep_b_kernel<<<UNITS / 64, 256, 0, stream>>>(mu, Bt, musq);
    rbf_gemm_kernel<<<dim3(BATCH / 256, UNITS / 256), 512, 0, stream>>>(
        inputs, Bt, musq, out);
}